// Round 12
// baseline (448.861 us; speedup 1.0000x reference)
//
#include <hip/hip_runtime.h>

#define N_NODES 8192
#define IN_F    256
#define OUT_F   128
#define ALPHA_S 0.2f

typedef __attribute__((ext_vector_type(8))) short  short8;
typedef __attribute__((ext_vector_type(4))) short  short4v;
typedef __attribute__((ext_vector_type(4))) float  floatx4;
typedef __attribute__((ext_vector_type(4))) int    intx4;
typedef __attribute__((ext_vector_type(4))) float  fx4;

static __device__ __forceinline__ float bf2f(short s) {
    union { unsigned int i; float f; } u;
    u.i = ((unsigned int)(unsigned short)s) << 16;
    return u.f;
}
static __device__ __forceinline__ short f2bf(float f) {
    union { float f; unsigned int i; } u; u.f = f;
    unsigned int r = u.i + 0x7FFFu + ((u.i >> 16) & 1u);  // RNE
    return (short)(r >> 16);
}

// ---------------------------------------------------------------------------
// k_wh: Wh = h @ W via bf16 MFMA -> fragment-major WhB[jblk][ft][lane][8].
//       src/dst fp32-exact via q1=W@a1, q2=W@a2 folded into W staging.
// 256 blocks x 512 threads. (validated R10/R11; unchanged)
// ---------------------------------------------------------------------------
__global__ __launch_bounds__(512) void k_wh(
    const float* __restrict__ h, const float* __restrict__ W,
    const float* __restrict__ a,
    short* __restrict__ WhB, float* __restrict__ src, float* __restrict__ dst)
{
    __shared__ short Wt[OUT_F][IN_F + 8];
    __shared__ short htile[32][IN_F + 8];
    __shared__ float q1s[IN_F], q2s[IN_F];
    __shared__ short wh_t[OUT_F][40];

    const int t      = threadIdx.x;
    const int lane   = t & 63;
    const int wave   = t >> 6;
    const int r_base = blockIdx.x * 32;

#pragma unroll
    for (int rep = 0; rep < 4; ++rep) {
        const int idx = rep * 8192 + t * 16;
        const int k   = idx >> 7;
        const int f   = idx & 127;
        fx4 w0 = *(const fx4*)(W + idx);
        fx4 w1 = *(const fx4*)(W + idx + 4);
        fx4 w2 = *(const fx4*)(W + idx + 8);
        fx4 w3 = *(const fx4*)(W + idx + 12);
        fx4 a10 = *(const fx4*)(a + f);
        fx4 a11 = *(const fx4*)(a + f + 4);
        fx4 a12 = *(const fx4*)(a + f + 8);
        fx4 a13 = *(const fx4*)(a + f + 12);
        fx4 a20 = *(const fx4*)(a + OUT_F + f);
        fx4 a21 = *(const fx4*)(a + OUT_F + f + 4);
        fx4 a22 = *(const fx4*)(a + OUT_F + f + 8);
        fx4 a23 = *(const fx4*)(a + OUT_F + f + 12);
        float p1 = 0.f, p2 = 0.f;
#pragma unroll
        for (int e = 0; e < 4; ++e) {
            p1 = fmaf(w0[e], a10[e], p1); p2 = fmaf(w0[e], a20[e], p2);
            p1 = fmaf(w1[e], a11[e], p1); p2 = fmaf(w1[e], a21[e], p2);
            p1 = fmaf(w2[e], a12[e], p1); p2 = fmaf(w2[e], a22[e], p2);
            p1 = fmaf(w3[e], a13[e], p1); p2 = fmaf(w3[e], a23[e], p2);
        }
#pragma unroll
        for (int e = 0; e < 4; ++e) {
            Wt[f + e][k]      = f2bf(w0[e]);
            Wt[f + 4 + e][k]  = f2bf(w1[e]);
            Wt[f + 8 + e][k]  = f2bf(w2[e]);
            Wt[f + 12 + e][k] = f2bf(w3[e]);
        }
#pragma unroll
        for (int m = 1; m < 8; m <<= 1) {
            p1 += __shfl_xor(p1, m, 64);
            p2 += __shfl_xor(p2, m, 64);
        }
        if ((t & 7) == 0) { q1s[k] = p1; q2s[k] = p2; }
    }

    const int r0   = t >> 4;
    const int fgrp = t & 15;
    const int k0   = fgrp * 16;
    fx4 h0, h1, h2, h3;
    {
        const float* hp = h + (size_t)(r_base + r0) * IN_F + k0;
        h0 = *(const fx4*)hp; h1 = *(const fx4*)(hp + 4);
        h2 = *(const fx4*)(hp + 8); h3 = *(const fx4*)(hp + 12);
        short8 b0, b1;
#pragma unroll
        for (int e = 0; e < 4; ++e) {
            b0[e]     = f2bf(h0[e]); b0[4 + e] = f2bf(h1[e]);
            b1[e]     = f2bf(h2[e]); b1[4 + e] = f2bf(h3[e]);
        }
        *(short8*)&htile[r0][k0]     = b0;
        *(short8*)&htile[r0][k0 + 8] = b1;
    }
    __syncthreads();

    {
        float sp = 0.f, dp = 0.f;
#pragma unroll
        for (int e = 0; e < 4; ++e) {
            sp = fmaf(h0[e], q1s[k0 + e], sp);      dp = fmaf(h0[e], q2s[k0 + e], dp);
            sp = fmaf(h1[e], q1s[k0 + 4 + e], sp);  dp = fmaf(h1[e], q2s[k0 + 4 + e], dp);
            sp = fmaf(h2[e], q1s[k0 + 8 + e], sp);  dp = fmaf(h2[e], q2s[k0 + 8 + e], dp);
            sp = fmaf(h3[e], q1s[k0 + 12 + e], sp); dp = fmaf(h3[e], q2s[k0 + 12 + e], dp);
        }
#pragma unroll
        for (int m = 1; m < 16; m <<= 1) {
            sp += __shfl_xor(sp, m, 64);
            dp += __shfl_xor(dp, m, 64);
        }
        if (fgrp == 0) { src[r_base + r0] = sp; dst[r_base + r0] = dp; }
    }

    const int ln15 = lane & 15;
    const int q    = lane >> 4;
    const int f0   = wave * 16;
    floatx4 c0 = {0.f, 0.f, 0.f, 0.f};
    floatx4 c1 = {0.f, 0.f, 0.f, 0.f};
#pragma unroll
    for (int s = 0; s < 8; ++s) {
        short8 bf  = *(const short8*)&Wt[f0 + ln15][s * 32 + q * 8];
        short8 a0f = *(const short8*)&htile[ln15][s * 32 + q * 8];
        short8 a1f = *(const short8*)&htile[16 + ln15][s * 32 + q * 8];
        c0 = __builtin_amdgcn_mfma_f32_16x16x32_bf16(a0f, bf, c0, 0, 0, 0);
        c1 = __builtin_amdgcn_mfma_f32_16x16x32_bf16(a1f, bf, c1, 0, 0, 0);
    }
    {
        short4v p0, p1;
#pragma unroll
        for (int r = 0; r < 4; ++r) { p0[r] = f2bf(c0[r]); p1[r] = f2bf(c1[r]); }
        *(short4v*)&wh_t[f0 + ln15][q * 4]      = p0;
        *(short4v*)&wh_t[f0 + ln15][16 + q * 4] = p1;
    }
    __syncthreads();
    {
        const int ft2 = t >> 6;
        const int l2  = t & 63;
        const int n2  = l2 & 15;
        const int q2  = l2 >> 4;
        short8 v = *(const short8*)&wh_t[ft2 * 16 + n2][q2 * 8];
        *(short8*)(WhB + (((size_t)blockIdx.x * 8 + ft2) * 64 + l2) * 8) = v;
    }
}

// ---------------------------------------------------------------------------
// k_weights: adj stream -> exp weights -> A-FRAGMENT-MAJOR Pfrag + denoms.
// Block = (rowtile rt of 16 rows) x (colchunk cc of 256 j). 256 threads.
// Phase 1: wave reads ONE row x 256 j (1KB contiguous/instr), exp -> LDS.
// Phase 2: LDS -> Pfrag[rt][kblk][lane][8], 1KB contiguous stores.
// Row-sums of bf16-rounded weights -> denom_part[cc][row] (plain stores).
// grid 16384 = 512 rt x 32 cc.
// ---------------------------------------------------------------------------
__global__ __launch_bounds__(256) void k_weights(
    const int*   __restrict__ adj,
    const float* __restrict__ src,
    const float* __restrict__ dstv,
    short* __restrict__ Pfrag,        // [512][256][512] shorts (128 MiB)
    float* __restrict__ denom_part)   // [32][N] fp32
{
    __shared__ short wl[16][264];     // pad 8 shorts: rows shift 4 banks

    const int t    = threadIdx.x;
    const int lane = t & 63;
    const int wv   = t >> 6;          // 0..3
    const int rt   = blockIdx.x >> 5; // 0..511
    const int cc   = blockIdx.x & 31; // 0..31
    const int jb   = cc * 256;

    const fx4 dv = *(const fx4*)(dstv + jb + lane * 4);

#pragma unroll
    for (int p = 0; p < 4; ++p) {
        const int rloc = p * 4 + wv;
        const int row  = rt * 16 + rloc;
        const float srow = src[row];
        intx4 m = *(const intx4*)(adj + (size_t)row * N_NODES + jb + lane * 4);
        short4v w;
        float ls = 0.f;
#pragma unroll
        for (int e = 0; e < 4; ++e) {
            float x = srow + dv[e];
            float l = fmaxf(x, ALPHA_S * x);
            short b = (m[e] > 0) ? f2bf(__expf(l)) : (short)0;
            w[e] = b;
            ls += bf2f(b);
        }
        *(short4v*)&wl[rloc][lane * 4] = w;
#pragma unroll
        for (int s = 1; s < 64; s <<= 1) ls += __shfl_xor(ls, s, 64);
        if (lane == 0) denom_part[(size_t)cc * N_NODES + row] = ls;
    }
    __syncthreads();

    const int ln15 = lane & 15;
    const int q    = lane >> 4;
#pragma unroll
    for (int p = 0; p < 2; ++p) {
        const int kb = p * 4 + wv;    // local kblk 0..7
        short8 v = *(const short8*)&wl[ln15][kb * 32 + q * 8];
        *(short8*)(Pfrag + (((size_t)rt * 256) + (size_t)cc * 8 + kb) * 512
                   + lane * 8) = v;
    }
}

// ---------------------------------------------------------------------------
// k_pv: numer = P @ Wh. NO LDS, NO BARRIERS. Wave owns (rowtile-pair rp,
// k-chunk kc), loops 32 kblks; every load is one contiguous 16B/lane
// (A-frags from Pfrag, B-frags from WhB). 2-deep pipeline, distinct regs.
// grid 512 x 256 thr (2048 waves = 256 rp x 8 kc).
// ---------------------------------------------------------------------------
#define PVSPLIT 8
__global__ __launch_bounds__(256, 2) void k_pv(
    const short* __restrict__ Pfrag,  // [512][256][512]
    const short* __restrict__ WhB,    // [256][8][512]
    float* __restrict__ numer_part)   // [8][N][OUT_F] fp32
{
    const int t    = threadIdx.x;
    const int lane = t & 63;
    const int wv   = t >> 6;
    const int gw   = blockIdx.x * 4 + wv;  // 0..2047
    const int rp   = gw >> 3;              // 0..255
    const int kc   = gw & 7;               // 0..7

    const short* A0b = Pfrag + ((size_t)(rp * 2)     * 256) * 512 + lane * 8;
    const short* A1b = Pfrag + ((size_t)(rp * 2 + 1) * 256) * 512 + lane * 8;
    const short* Bb  = WhB + (size_t)lane * 8;

    floatx4 acc[2][8];
#pragma unroll
    for (int pr = 0; pr < 2; ++pr)
#pragma unroll
        for (int ft = 0; ft < 8; ++ft) acc[pr][ft] = (floatx4){0.f, 0.f, 0.f, 0.f};

    short8 A0[2], A1[2], B[2][8];

    auto load = [&](int i, int ph) {
        const size_t kblk = kc * 32 + i;
        A0[ph] = *(const short8*)(A0b + kblk * 512);
        A1[ph] = *(const short8*)(A1b + kblk * 512);
#pragma unroll
        for (int ft = 0; ft < 8; ++ft)
            B[ph][ft] = *(const short8*)(Bb + (kblk * 8 + ft) * 512);
    };
    auto comp = [&](int ph) {
#pragma unroll
        for (int ft = 0; ft < 8; ++ft) {
            acc[0][ft] = __builtin_amdgcn_mfma_f32_16x16x32_bf16(A0[ph], B[ph][ft], acc[0][ft], 0, 0, 0);
            acc[1][ft] = __builtin_amdgcn_mfma_f32_16x16x32_bf16(A1[ph], B[ph][ft], acc[1][ft], 0, 0, 0);
        }
    };

    load(0, 0);
    for (int i = 0; i < 32; i += 2) {
        if (i + 1 < 32) load(i + 1, 1);
        comp(0);
        if (i + 2 < 32) load(i + 2, 0);
        comp(1);
    }

    // store: rows rp*32 + pr*16 + q*4+r, col ft*16+ln15
    const int ln15 = lane & 15;
    const int q    = lane >> 4;
    float* np = numer_part + (size_t)kc * N_NODES * OUT_F;
#pragma unroll
    for (int pr = 0; pr < 2; ++pr)
#pragma unroll
        for (int ft = 0; ft < 8; ++ft)
#pragma unroll
            for (int r = 0; r < 4; ++r)
                np[(size_t)(rp * 32 + pr * 16 + q * 4 + r) * OUT_F + ft * 16 + ln15]
                    = acc[pr][ft][r];
}

// ---------------------------------------------------------------------------
// k_final: out = ELU( (sum_kc numer) / (sum_cc denom) ).
// denom==0 guard kept as diagnostic (inert upstream shows absmax~0.97).
// ---------------------------------------------------------------------------
__global__ void k_final(const float* __restrict__ numer_part,
                        const float* __restrict__ denom_part,
                        float* __restrict__ out) {
    const int idx = blockIdx.x * 256 + threadIdx.x;   // grid 4096
    const int row = idx >> 7;
    float v = 0.f;
#pragma unroll
    for (int kc = 0; kc < PVSPLIT; ++kc)
        v += numer_part[(size_t)kc * N_NODES * OUT_F + idx];
    float dn = 0.f;
#pragma unroll
    for (int cc = 0; cc < 32; ++cc)
        dn += denom_part[(size_t)cc * N_NODES + row];
    v = (dn != 0.f) ? (v / dn) : 0.f;
    v = v > 0.f ? v : (__expf(v) - 1.f);
    out[idx] = v;
}

// ---------------------------------------------------------------------------
extern "C" void kernel_launch(void* const* d_in, const int* in_sizes, int n_in,
                              void* d_out, int out_size, void* d_ws, size_t ws_size,
                              hipStream_t stream) {
    const float* h   = (const float*)d_in[0];   // fp32 [8192][256]
    const int*   adj = (const int*)d_in[1];     // int32 [8192][8192]
    const float* W   = (const float*)d_in[2];   // fp32 [256][128]
    const float* a   = (const float*)d_in[3];   // fp32 [256]
    float* out = (float*)d_out;                 // fp32 [8192][128]

    char*  ws         = (char*)d_ws;
    float* denom_part = (float*)ws;                             // 1 MiB [32][N]
    short* WhB        = (short*)(ws + (1 << 20));               // 2 MiB
    float* src        = (float*)(ws + (3 << 20));               // 32 KB
    float* dst        = src + N_NODES;                          // 32 KB
    float* numer_part = (float*)(ws + (4 << 20));               // 32 MiB
    short* Pfrag      = (short*)(ws + (64ull << 20));           // 128 MiB

    k_wh      <<<256, 512, 0, stream>>>(h, W, a, WhB, src, dst);
    k_weights <<<16384, 256, 0, stream>>>(adj, src, dst, Pfrag, denom_part);
    k_pv      <<<512, 256, 0, stream>>>(Pfrag, WhB, numer_part);
    k_final   <<<4096, 256, 0, stream>>>(numer_part, denom_part, out);
}